// Round 7
// baseline (1190.275 us; speedup 1.0000x reference)
//
#include <hip/hip_runtime.h>
#include <stdint.h>

// B=512, S=512, F=64, H=128, 4H=512, O=64
#define SEQ 512
#define HID 128

typedef short bf16x8 __attribute__((ext_vector_type(8)));   // 8 bf16 = 4 VGPR
typedef float f32x4v __attribute__((ext_vector_type(4)));   // MFMA acc

#define MFMA16(a, b, c) __builtin_amdgcn_mfma_f32_16x16x32_bf16((a), (b), (c), 0, 0, 0)

__device__ __forceinline__ uint32_t bfr(float f) {          // fp32 -> bf16 (RNE)
    uint32_t u = __float_as_uint(f);
    return (u + 0x7fffu + ((u >> 16) & 1u)) >> 16;
}
__device__ __forceinline__ uint32_t bfp(float a, float b) { // pack 2 bf16
    return bfr(a) | (bfr(b) << 16);
}
__device__ __forceinline__ float fsig(float x) {
    return __builtin_amdgcn_rcpf(1.0f + __expf(-x));
}
__device__ __forceinline__ float ftanh(float x) {
    return 1.0f - 2.0f * __builtin_amdgcn_rcpf(__expf(2.0f * x) + 1.0f);
}

// A-fragment: lane holds W[row][k0 .. k0+7] as bf16x8 (row = base + lane&15).
__device__ __forceinline__ bf16x8 afrag(const float* W, int row, int K, int k0) {
    const float4* p = (const float4*)(W + (size_t)row * K + k0);
    float4 a = p[0], b = p[1];
    union { bf16x8 v; uint32_t u[4]; } f;
    f.u[0] = bfp(a.x, a.y); f.u[1] = bfp(a.z, a.w);
    f.u[2] = bfp(b.x, b.y); f.u[3] = bfp(b.z, b.w);
    return f.v;
}

// stage 2 fp32 x-values as bf16 hi (offset 0) + residual lo (offset 2048), swizzled
__device__ __forceinline__ void stage_x(uint8_t* dst, int xrb, int xf0, float2 v) {
    uint32_t hx = bfr(v.x), hy = bfr(v.y);
    float rx = v.x - __uint_as_float(hx << 16);
    float ry = v.y - __uint_as_float(hy << 16);
    int kb = (2 * xf0) ^ ((xrb & 7) << 4);
    *(uint32_t*)(dst + xrb * 128 + kb) = hx | (hy << 16);
    *(uint32_t*)(dst + 2048 + xrb * 128 + kb) = bfr(rx) | (bfr(ry) << 16);
}

// hseq granule layout (bf16): granule g = t*8192 + bblk*256 + jblk*16 + b, elems g*8+ji
//   (per t: 32 bblk x 16 jblk x 16 b = 8192 granules)

// =============== L0: gates(t) = [carried Wih@x(t)] + Whh@h(t); writes hseq ===============
// Off-critical-path input projection: during step t, acc_next = bias + Wih@x(t+1)
// (independent of h(t)) overlaps with the activation chain. On-path: 4-deep Whh MFMA.
__global__ __launch_bounds__(512, 2) void rec0(
    const float* __restrict__ x, const float* __restrict__ Wih,
    const float* __restrict__ Whh, const float* __restrict__ bih,
    const float* __restrict__ bhh, unsigned short* __restrict__ hseq)
{
    const int tid = threadIdx.x, wid = tid >> 6, lane = tid & 63;
    const int l15 = lane & 15, lg = lane >> 4;
    const int bblk = blockIdx.x, bb = bblk * 16, jb = wid * 16;

    __shared__ __align__(16) uint8_t lds[16384];
    uint8_t* hbuf = lds;            // 2 x 4096 h dbuf (bf16, swizzled)
    uint8_t* xbuf = lds + 8192;     // 2 par x (hi 2KB + lo 2KB)

    bf16x8 wih[4][2], whh[4][4];
    f32x4v bias[4];
#pragma unroll
    for (int c = 0; c < 4; c++) {
        int row = c * 128 + jb + l15;
#pragma unroll
        for (int kt = 0; kt < 2; kt++) wih[c][kt] = afrag(Wih, row, 64, kt * 32 + lg * 8);
#pragma unroll
        for (int kt = 0; kt < 4; kt++) whh[c][kt] = afrag(Whh, row, 128, kt * 32 + lg * 8);
#pragma unroll
        for (int e = 0; e < 4; e++) {
            int gr = c * 128 + jb + lg * 4 + e;
            bias[c][e] = bih[gr] + bhh[gr];
        }
    }

    const int xrb = tid >> 5, xf0 = (tid & 31) * 2;
    const size_t xbase = (size_t)(bb + xrb) * SEQ * 64 + xf0;
    const int swz = (l15 & 7) << 4;

    // prologue: zero hbuf, stage x(0) -> xbuf[0]
    *(f32x4v*)(lds + tid * 16) = f32x4v{0.f, 0.f, 0.f, 0.f};  // covers hbuf 8KB
    stage_x(xbuf, xrb, xf0, *(const float2*)(x + xbase));
    __syncthreads();
    // acc_carried(t=0) = bias + Wih@x(0)
    f32x4v acc[4];
    {
        bf16x8 xhf[2], xlf[2];
#pragma unroll
        for (int kt = 0; kt < 2; kt++) {
            int kb = (2 * (kt * 32 + lg * 8)) ^ swz;
            xhf[kt] = *(const bf16x8*)(xbuf + l15 * 128 + kb);
            xlf[kt] = *(const bf16x8*)(xbuf + 2048 + l15 * 128 + kb);
        }
#pragma unroll
        for (int c = 0; c < 4; c++) {
            f32x4v a = MFMA16(wih[c][0], xhf[0], bias[c]);
            a = MFMA16(wih[c][1], xhf[1], a);
            a = MFMA16(wih[c][0], xlf[0], a);
            a = MFMA16(wih[c][1], xlf[1], a);
            acc[c] = a;
        }
    }
    // stage x(1) -> xbuf[1]
    stage_x(xbuf + 4096, xrb, xf0, *(const float2*)(x + xbase + 64));
    __syncthreads();

    float cst[4] = {0.f, 0.f, 0.f, 0.f};
    const int j0 = jb + lg * 4;
    const int hwb = l15 * 256 + ((2 * j0) ^ ((l15 & 7) << 4));

    for (int t = 0; t < SEQ; t++) {
        const int p = t & 1;
        // h(t) B-frags from hbuf[p]
        const uint8_t* hb = hbuf + p * 4096;
        bf16x8 hf[4];
#pragma unroll
        for (int kt = 0; kt < 4; kt++) {
            int kb = (2 * (kt * 32 + lg * 8)) ^ swz;
            hf[kt] = *(const bf16x8*)(hb + l15 * 256 + kb);
        }
        // issue x(t+2) global load
        float2 xv = {0.f, 0.f};
        if (t + 2 < SEQ) xv = *(const float2*)(x + xbase + (size_t)(t + 2) * 64);
        // x(t+1) frags from xbuf[p^1] (staged at step t-1)
        const uint8_t* xh = xbuf + (p ^ 1) * 4096;
        bf16x8 xhf[2], xlf[2];
#pragma unroll
        for (int kt = 0; kt < 2; kt++) {
            int kb = (2 * (kt * 32 + lg * 8)) ^ swz;
            xhf[kt] = *(const bf16x8*)(xh + l15 * 128 + kb);
            xlf[kt] = *(const bf16x8*)(xh + 2048 + l15 * 128 + kb);
        }

        // on-path: gates = acc_carried + Whh@h(t)   (4-deep chain per c)
        f32x4v g4[4];
#pragma unroll
        for (int c = 0; c < 4; c++) {
            f32x4v a = MFMA16(whh[c][0], hf[0], acc[c]);
#pragma unroll
            for (int kt = 1; kt < 4; kt++) a = MFMA16(whh[c][kt], hf[kt], a);
            g4[c] = a;
        }
        // off-path: acc_next = bias + Wih@x(t+1)
        f32x4v accn[4];
#pragma unroll
        for (int c = 0; c < 4; c++) {
            f32x4v a = MFMA16(wih[c][0], xhf[0], bias[c]);
            a = MFMA16(wih[c][1], xhf[1], a);
            a = MFMA16(wih[c][0], xlf[0], a);
            a = MFMA16(wih[c][1], xlf[1], a);
            accn[c] = a;
        }

        // activations + state update (lane owns b=l15, j=j0..j0+3)
        float h[4];
#pragma unroll
        for (int e = 0; e < 4; e++) {
            float ig = fsig(g4[0][e]);
            float fg = fsig(g4[1][e]);
            float gg = ftanh(g4[2][e]);
            float og = fsig(g4[3][e]);
            float cv = fg * cst[e] + ig * gg;
            cst[e] = cv;
            h[e] = og * ftanh(cv);
        }
        uint32_t hp0 = bfp(h[0], h[1]), hp1 = bfp(h[2], h[3]);
        *(uint2*)(hbuf + (p ^ 1) * 4096 + hwb) = make_uint2(hp0, hp1);
        int gidx = (((t * 32 + bblk) * 16 + (j0 >> 3)) * 16 + l15) * 8 + (j0 & 7);
        *(uint2*)(hseq + gidx) = make_uint2(hp0, hp1);

        // stage x(t+2) into xbuf[p] (read at step t+1)
        if (t + 2 < SEQ) stage_x(xbuf + p * 4096, xrb, xf0, xv);

        // raw barrier: LDS drain only; global store + x loads stay in flight
        asm volatile("s_waitcnt lgkmcnt(0)\n\ts_barrier" ::: "memory");
#pragma unroll
        for (int c = 0; c < 4; c++) acc[c] = accn[c];
    }
}

// =============== L1 + FC: gates(t) = [carried Wih@h0(t)] + Whh@h1(t) ===============
// h0(t+1) kept in 2-deep static register banks (A/B by step parity).
__global__ __launch_bounds__(512, 2) void rec1fc(
    const unsigned short* __restrict__ hseq, const float* __restrict__ Wih,
    const float* __restrict__ Whh, const float* __restrict__ bih,
    const float* __restrict__ bhh, const float* __restrict__ fcw,
    const float* __restrict__ fcb, float* __restrict__ out)
{
    const int tid = threadIdx.x, wid = tid >> 6, lane = tid & 63;
    const int l15 = lane & 15, lg = lane >> 4;
    const int bblk = blockIdx.x, bb = bblk * 16, jb = wid * 16;

    __shared__ __align__(16) uint8_t lds[16384];  // 8K h1 dbuf + 8K f32 hfin
    float* hfin = (float*)(lds + 8192);

    bf16x8 wih[4][4], whh[4][4];
    f32x4v bias[4];
#pragma unroll
    for (int c = 0; c < 4; c++) {
        int row = c * 128 + jb + l15;
#pragma unroll
        for (int kt = 0; kt < 4; kt++) {
            wih[c][kt] = afrag(Wih, row, 128, kt * 32 + lg * 8);
            whh[c][kt] = afrag(Whh, row, 128, kt * 32 + lg * 8);
        }
#pragma unroll
        for (int e = 0; e < 4; e++) {
            int gr = c * 128 + jb + lg * 4 + e;
            bias[c][e] = bih[gr] + bhh[gr];
        }
    }

    const int swz = (l15 & 7) << 4;
    // h0 granule for (t, kt): t*8192 + bblk*256 + (kt*4+lg)*16 + l15   [FIXED: was t*512]
    const size_t gbase = (size_t)bblk * 256 + lg * 16 + l15;

    // prologue: acc_carried(0) = bias + Wih@h0(0)
    f32x4v acc[4];
    {
        bf16x8 f0[4];
#pragma unroll
        for (int kt = 0; kt < 4; kt++)
            f0[kt] = *(const bf16x8*)(hseq + (gbase + kt * 64) * 8);
#pragma unroll
        for (int c = 0; c < 4; c++) {
            f32x4v a = MFMA16(wih[c][0], f0[0], bias[c]);
#pragma unroll
            for (int kt = 1; kt < 4; kt++) a = MFMA16(wih[c][kt], f0[kt], a);
            acc[c] = a;
        }
    }
    // h0(1) -> bank A
    bf16x8 h0A[4], h0B[4];
#pragma unroll
    for (int kt = 0; kt < 4; kt++)
        h0A[kt] = *(const bf16x8*)(hseq + (gbase + (size_t)1 * 8192 + kt * 64) * 8);

    *(f32x4v*)(lds + tid * 16) = f32x4v{0.f, 0.f, 0.f, 0.f};   // zero h1 dbuf
    __syncthreads();

    float cst[4] = {0.f, 0.f, 0.f, 0.f};
    const int j0 = jb + lg * 4;
    const int hwb = l15 * 256 + ((2 * j0) ^ ((l15 & 7) << 4));

    for (int tp = 0; tp < SEQ / 2; tp++) {
#pragma unroll
        for (int ph = 0; ph < 2; ph++) {            // static bank parity
            const int t = 2 * tp + ph;
            const uint8_t* hb = lds + ph * 4096;
            bf16x8 hf[4];
#pragma unroll
            for (int kt = 0; kt < 4; kt++) {
                int kb = (2 * (kt * 32 + lg * 8)) ^ swz;
                hf[kt] = *(const bf16x8*)(hb + l15 * 256 + kb);
            }
            // issue h0(t+2) loads into the dead bank
            if (t + 2 < SEQ) {
#pragma unroll
                for (int kt = 0; kt < 4; kt++) {
                    const bf16x8 v = *(const bf16x8*)(hseq + (gbase + (size_t)(t + 2) * 8192 + kt * 64) * 8);
                    if (ph == 0) h0B[kt] = v; else h0A[kt] = v;
                }
            }

            // on-path: gates = acc_carried + Whh@h1(t)
            f32x4v g4[4];
#pragma unroll
            for (int c = 0; c < 4; c++) {
                f32x4v a = MFMA16(whh[c][0], hf[0], acc[c]);
#pragma unroll
                for (int kt = 1; kt < 4; kt++) a = MFMA16(whh[c][kt], hf[kt], a);
                g4[c] = a;
            }
            // off-path: acc_next = bias + Wih@h0(t+1)  (bank by parity)
            f32x4v accn[4];
#pragma unroll
            for (int c = 0; c < 4; c++) {
                f32x4v a;
                if (ph == 0) {
                    a = MFMA16(wih[c][0], h0A[0], bias[c]);
#pragma unroll
                    for (int kt = 1; kt < 4; kt++) a = MFMA16(wih[c][kt], h0A[kt], a);
                } else {
                    a = MFMA16(wih[c][0], h0B[0], bias[c]);
#pragma unroll
                    for (int kt = 1; kt < 4; kt++) a = MFMA16(wih[c][kt], h0B[kt], a);
                }
                accn[c] = a;
            }

            float h[4];
#pragma unroll
            for (int e = 0; e < 4; e++) {
                float ig = fsig(g4[0][e]);
                float fg = fsig(g4[1][e]);
                float gg = ftanh(g4[2][e]);
                float og = fsig(g4[3][e]);
                float cv = fg * cst[e] + ig * gg;
                cst[e] = cv;
                h[e] = og * ftanh(cv);
            }
            *(uint2*)(lds + (ph ^ 1) * 4096 + hwb) =
                make_uint2(bfp(h[0], h[1]), bfp(h[2], h[3]));
            if (ph == 1 && t == SEQ - 1)
                *(f32x4v*)(hfin + l15 * HID + j0) = f32x4v{h[0], h[1], h[2], h[3]};

            asm volatile("s_waitcnt lgkmcnt(0)\n\ts_barrier" ::: "memory");
#pragma unroll
            for (int c = 0; c < 4; c++) acc[c] = accn[c];
        }
    }
    __syncthreads();

    // fused FC: out[b][o] = relu(h1).fcw[o] + fcb[o]
    const int fb = tid >> 5, op = (tid & 31) * 2;
    float a0 = fcb[op], a1 = fcb[op + 1];
    const float4* w0 = (const float4*)(fcw + op * HID);
    const float4* w1 = (const float4*)(fcw + (op + 1) * HID);
    const float4* hv4 = (const float4*)(hfin + fb * HID);
#pragma unroll 8
    for (int k = 0; k < 32; k++) {
        float4 hv = hv4[k];
        float r0 = fmaxf(hv.x, 0.f), r1 = fmaxf(hv.y, 0.f);
        float r2 = fmaxf(hv.z, 0.f), r3 = fmaxf(hv.w, 0.f);
        float4 wa = w0[k], wb = w1[k];
        a0 += r0 * wa.x + r1 * wa.y + r2 * wa.z + r3 * wa.w;
        a1 += r0 * wb.x + r1 * wb.y + r2 * wb.z + r3 * wb.w;
    }
    out[(bb + fb) * 64 + op] = a0;
    out[(bb + fb) * 64 + op + 1] = a1;
}

extern "C" void kernel_launch(void* const* d_in, const int* in_sizes, int n_in,
                              void* d_out, int out_size, void* d_ws, size_t ws_size,
                              hipStream_t stream) {
    const float* x    = (const float*)d_in[0];
    const float* Wih0 = (const float*)d_in[1];
    const float* Whh0 = (const float*)d_in[2];
    const float* bih0 = (const float*)d_in[3];
    const float* bhh0 = (const float*)d_in[4];
    const float* Wih1 = (const float*)d_in[5];
    const float* Whh1 = (const float*)d_in[6];
    const float* bih1 = (const float*)d_in[7];
    const float* bhh1 = (const float*)d_in[8];
    const float* fcw  = (const float*)d_in[9];
    const float* fcb  = (const float*)d_in[10];

    // ws: hseq bf16 granules, 64 MiB
    unsigned short* hseq = (unsigned short*)d_ws;

    rec0<<<32, 512, 0, stream>>>(x, Wih0, Whh0, bih0, bhh0, hseq);
    rec1fc<<<32, 512, 0, stream>>>(hseq, Wih1, Whh1, bih1, bhh1, fcw, fcb, (float*)d_out);
}

// Round 8
// 736.774 us; speedup vs baseline: 1.6155x; 1.6155x over previous
//
#include <hip/hip_runtime.h>
#include <stdint.h>

// B=512, S=512, F=64, H=128, 4H=512, O=64
#define SEQ 512
#define HID 128
#define CH 16            // pipeline chunk (steps) ; NCHUNK = 32

typedef short bf16x8 __attribute__((ext_vector_type(8)));   // 8 bf16 = 4 VGPR
typedef float f32x4v __attribute__((ext_vector_type(4)));   // MFMA acc

#define MFMA16(a, b, c) __builtin_amdgcn_mfma_f32_16x16x32_bf16((a), (b), (c), 0, 0, 0)

__device__ __forceinline__ uint32_t bfr(float f) {          // fp32 -> bf16 (RNE)
    uint32_t u = __float_as_uint(f);
    return (u + 0x7fffu + ((u >> 16) & 1u)) >> 16;
}
__device__ __forceinline__ uint32_t bfp(float a, float b) { // pack 2 bf16
    return bfr(a) | (bfr(b) << 16);
}
__device__ __forceinline__ float fsig(float x) {
    return __builtin_amdgcn_rcpf(1.0f + __expf(-x));
}
__device__ __forceinline__ float ftanh(float x) {
    return 1.0f - 2.0f * __builtin_amdgcn_rcpf(__expf(2.0f * x) + 1.0f);
}

// A-fragment: lane holds W[row][k0 .. k0+7] as bf16x8 (row = base + lane&15).
__device__ __forceinline__ bf16x8 afrag(const float* W, int row, int K, int k0) {
    const float4* p = (const float4*)(W + (size_t)row * K + k0);
    float4 a = p[0], b = p[1];
    union { bf16x8 v; uint32_t u[4]; } f;
    f.u[0] = bfp(a.x, a.y); f.u[1] = bfp(a.z, a.w);
    f.u[2] = bfp(b.x, b.y); f.u[3] = bfp(b.z, b.w);
    return f.v;
}

// stage 2 fp32 x-values as bf16 hi (offset 0) + residual lo (offset 2048), swizzled
__device__ __forceinline__ void stage_x(uint8_t* dst, int xrb, int xf0, float2 v) {
    uint32_t hx = bfr(v.x), hy = bfr(v.y);
    float rx = v.x - __uint_as_float(hx << 16);
    float ry = v.y - __uint_as_float(hy << 16);
    int kb = (2 * xf0) ^ ((xrb & 7) << 4);
    *(uint32_t*)(dst + xrb * 128 + kb) = hx | (hy << 16);
    *(uint32_t*)(dst + 2048 + xrb * 128 + kb) = bfr(rx) | (bfr(ry) << 16);
}

// consumer-side chunk gate: tid0 acquire-spins, block joins at barrier
__device__ __forceinline__ void wait_flag(int* flags, int src, int need, int tid) {
    if (tid == 0) {
        for (long c = 0; c < 200000000L; ++c) {
            int v = __hip_atomic_load(flags + src, __ATOMIC_ACQUIRE,
                                      __HIP_MEMORY_SCOPE_AGENT);
            if (v >= need) break;
            __builtin_amdgcn_s_sleep(2);
        }
    }
    __syncthreads();
}

// hseq granule layout (bf16): granule g = t*8192 + bblk*256 + jblk*16 + b, elems g*8+ji

// =============== L0 role: gates(t)=[carried Wih@x(t)]+Whh@h(t); publish chunks ===============
__device__ __forceinline__ void l0_body(
    uint8_t* lds, const float* __restrict__ x, const float* __restrict__ Wih,
    const float* __restrict__ Whh, const float* __restrict__ bih,
    const float* __restrict__ bhh, unsigned short* __restrict__ hseq, int* flags)
{
    const int tid = threadIdx.x, wid = tid >> 6, lane = tid & 63;
    const int l15 = lane & 15, lg = lane >> 4;
    const int bblk = blockIdx.x, bb = bblk * 16, jb = wid * 16;

    uint8_t* hbuf = lds;            // 2 x 4096 h dbuf (bf16, swizzled)
    uint8_t* xbuf = lds + 8192;     // 2 par x (hi 2KB + lo 2KB)

    bf16x8 wih[4][2], whh[4][4];
    f32x4v bias[4];
#pragma unroll
    for (int c = 0; c < 4; c++) {
        int row = c * 128 + jb + l15;
#pragma unroll
        for (int kt = 0; kt < 2; kt++) wih[c][kt] = afrag(Wih, row, 64, kt * 32 + lg * 8);
#pragma unroll
        for (int kt = 0; kt < 4; kt++) whh[c][kt] = afrag(Whh, row, 128, kt * 32 + lg * 8);
#pragma unroll
        for (int e = 0; e < 4; e++) {
            int gr = c * 128 + jb + lg * 4 + e;
            bias[c][e] = bih[gr] + bhh[gr];
        }
    }

    const int xrb = tid >> 5, xf0 = (tid & 31) * 2;
    const size_t xbase = (size_t)(bb + xrb) * SEQ * 64 + xf0;
    const int swz = (l15 & 7) << 4;

    *(f32x4v*)(lds + tid * 16) = f32x4v{0.f, 0.f, 0.f, 0.f};  // zero hbuf 8KB
    stage_x(xbuf, xrb, xf0, *(const float2*)(x + xbase));
    __syncthreads();
    f32x4v acc[4];
    {
        bf16x8 xhf[2], xlf[2];
#pragma unroll
        for (int kt = 0; kt < 2; kt++) {
            int kb = (2 * (kt * 32 + lg * 8)) ^ swz;
            xhf[kt] = *(const bf16x8*)(xbuf + l15 * 128 + kb);
            xlf[kt] = *(const bf16x8*)(xbuf + 2048 + l15 * 128 + kb);
        }
#pragma unroll
        for (int c = 0; c < 4; c++) {
            f32x4v a = MFMA16(wih[c][0], xhf[0], bias[c]);
            a = MFMA16(wih[c][1], xhf[1], a);
            a = MFMA16(wih[c][0], xlf[0], a);
            a = MFMA16(wih[c][1], xlf[1], a);
            acc[c] = a;
        }
    }
    stage_x(xbuf + 4096, xrb, xf0, *(const float2*)(x + xbase + 64));
    __syncthreads();

    float cst[4] = {0.f, 0.f, 0.f, 0.f};
    const int j0 = jb + lg * 4;
    const int hwb = l15 * 256 + ((2 * j0) ^ ((l15 & 7) << 4));

    for (int t = 0; t < SEQ; t++) {
        const int p = t & 1;
        const uint8_t* hb = hbuf + p * 4096;
        bf16x8 hf[4];
#pragma unroll
        for (int kt = 0; kt < 4; kt++) {
            int kb = (2 * (kt * 32 + lg * 8)) ^ swz;
            hf[kt] = *(const bf16x8*)(hb + l15 * 256 + kb);
        }
        float2 xv = {0.f, 0.f};
        if (t + 2 < SEQ) xv = *(const float2*)(x + xbase + (size_t)(t + 2) * 64);
        const uint8_t* xh = xbuf + (p ^ 1) * 4096;
        bf16x8 xhf[2], xlf[2];
#pragma unroll
        for (int kt = 0; kt < 2; kt++) {
            int kb = (2 * (kt * 32 + lg * 8)) ^ swz;
            xhf[kt] = *(const bf16x8*)(xh + l15 * 128 + kb);
            xlf[kt] = *(const bf16x8*)(xh + 2048 + l15 * 128 + kb);
        }

        f32x4v g4[4];
#pragma unroll
        for (int c = 0; c < 4; c++) {
            f32x4v a = MFMA16(whh[c][0], hf[0], acc[c]);
#pragma unroll
            for (int kt = 1; kt < 4; kt++) a = MFMA16(whh[c][kt], hf[kt], a);
            g4[c] = a;
        }
        f32x4v accn[4];
#pragma unroll
        for (int c = 0; c < 4; c++) {
            f32x4v a = MFMA16(wih[c][0], xhf[0], bias[c]);
            a = MFMA16(wih[c][1], xhf[1], a);
            a = MFMA16(wih[c][0], xlf[0], a);
            a = MFMA16(wih[c][1], xlf[1], a);
            accn[c] = a;
        }

        float h[4];
#pragma unroll
        for (int e = 0; e < 4; e++) {
            float ig = fsig(g4[0][e]);
            float fg = fsig(g4[1][e]);
            float gg = ftanh(g4[2][e]);
            float og = fsig(g4[3][e]);
            float cv = fg * cst[e] + ig * gg;
            cst[e] = cv;
            h[e] = og * ftanh(cv);
        }
        uint32_t hp0 = bfp(h[0], h[1]), hp1 = bfp(h[2], h[3]);
        *(uint2*)(hbuf + (p ^ 1) * 4096 + hwb) = make_uint2(hp0, hp1);
        int gidx = (((t * 32 + bblk) * 16 + (j0 >> 3)) * 16 + l15) * 8 + (j0 & 7);
        *(uint2*)(hseq + gidx) = make_uint2(hp0, hp1);

        if (t + 2 < SEQ) stage_x(xbuf + p * 4096, xrb, xf0, xv);

        asm volatile("s_waitcnt lgkmcnt(0)\n\ts_barrier" ::: "memory");

        // publish chunk: all stores drained -> barrier -> L2 writeback -> release flag
        if (((t + 1) & (CH - 1)) == 0) {
            asm volatile("s_waitcnt vmcnt(0)" ::: "memory");
            __syncthreads();
            if (tid == 0) {
                __threadfence();
                __hip_atomic_store(flags + bblk, (t + 1) / CH, __ATOMIC_RELEASE,
                                   __HIP_MEMORY_SCOPE_AGENT);
            }
        }
#pragma unroll
        for (int c = 0; c < 4; c++) acc[c] = accn[c];
    }
}

// =============== L1 role + FC: gates(t)=[carried Wih@h0(t)]+Whh@h1(t) ===============
__device__ __forceinline__ void l1_body(
    uint8_t* lds, const unsigned short* __restrict__ hseq,
    const float* __restrict__ Wih, const float* __restrict__ Whh,
    const float* __restrict__ bih, const float* __restrict__ bhh,
    const float* __restrict__ fcw, const float* __restrict__ fcb,
    float* __restrict__ out, int* flags)
{
    const int tid = threadIdx.x, wid = tid >> 6, lane = tid & 63;
    const int l15 = lane & 15, lg = lane >> 4;
    const int bblk = blockIdx.x - 32, bb = bblk * 16, jb = wid * 16;

    float* hfin = (float*)(lds + 8192);

    bf16x8 wih[4][4], whh[4][4];
    f32x4v bias[4];
#pragma unroll
    for (int c = 0; c < 4; c++) {
        int row = c * 128 + jb + l15;
#pragma unroll
        for (int kt = 0; kt < 4; kt++) {
            wih[c][kt] = afrag(Wih, row, 128, kt * 32 + lg * 8);
            whh[c][kt] = afrag(Whh, row, 128, kt * 32 + lg * 8);
        }
#pragma unroll
        for (int e = 0; e < 4; e++) {
            int gr = c * 128 + jb + lg * 4 + e;
            bias[c][e] = bih[gr] + bhh[gr];
        }
    }

    const int swz = (l15 & 7) << 4;
    // h0 granule for (t,kt): t*8192 + bblk*256 + (kt*4+lg)*16 + l15
    const size_t gbase = (size_t)bblk * 256 + lg * 16 + l15;

    wait_flag(flags, bblk, 2, tid);          // h0 steps 0..31 available

    f32x4v acc[4];
    {
        bf16x8 f0[4];
#pragma unroll
        for (int kt = 0; kt < 4; kt++)
            f0[kt] = *(const bf16x8*)(hseq + (gbase + kt * 64) * 8);
#pragma unroll
        for (int c = 0; c < 4; c++) {
            f32x4v a = MFMA16(wih[c][0], f0[0], bias[c]);
#pragma unroll
            for (int kt = 1; kt < 4; kt++) a = MFMA16(wih[c][kt], f0[kt], a);
            acc[c] = a;
        }
    }
    bf16x8 h0A[4], h0B[4];
#pragma unroll
    for (int kt = 0; kt < 4; kt++)
        h0A[kt] = *(const bf16x8*)(hseq + (gbase + (size_t)1 * 8192 + kt * 64) * 8);

    *(f32x4v*)(lds + tid * 16) = f32x4v{0.f, 0.f, 0.f, 0.f};   // zero h1 dbuf
    __syncthreads();

    float cst[4] = {0.f, 0.f, 0.f, 0.f};
    const int j0 = jb + lg * 4;
    const int hwb = l15 * 256 + ((2 * j0) ^ ((l15 & 7) << 4));

    for (int tp = 0; tp < SEQ / 2; tp++) {
        // chunk gate: steps 2tp.. need h0 through 2tp+17 -> flag >= tp/8 + 2
        if (tp && !(tp & 7)) {
            int need = tp / 8 + 2;
            wait_flag(flags, bblk, need > 32 ? 32 : need, tid);
        }
#pragma unroll
        for (int ph = 0; ph < 2; ph++) {            // static bank parity
            const int t = 2 * tp + ph;
            const uint8_t* hb = lds + ph * 4096;
            bf16x8 hf[4];
#pragma unroll
            for (int kt = 0; kt < 4; kt++) {
                int kb = (2 * (kt * 32 + lg * 8)) ^ swz;
                hf[kt] = *(const bf16x8*)(hb + l15 * 256 + kb);
            }
            if (t + 2 < SEQ) {
#pragma unroll
                for (int kt = 0; kt < 4; kt++) {
                    const bf16x8 v = *(const bf16x8*)(hseq + (gbase + (size_t)(t + 2) * 8192 + kt * 64) * 8);
                    if (ph == 0) h0B[kt] = v; else h0A[kt] = v;
                }
            }

            f32x4v g4[4];
#pragma unroll
            for (int c = 0; c < 4; c++) {
                f32x4v a = MFMA16(whh[c][0], hf[0], acc[c]);
#pragma unroll
                for (int kt = 1; kt < 4; kt++) a = MFMA16(whh[c][kt], hf[kt], a);
                g4[c] = a;
            }
            f32x4v accn[4];
#pragma unroll
            for (int c = 0; c < 4; c++) {
                f32x4v a;
                if (ph == 0) {
                    a = MFMA16(wih[c][0], h0A[0], bias[c]);
#pragma unroll
                    for (int kt = 1; kt < 4; kt++) a = MFMA16(wih[c][kt], h0A[kt], a);
                } else {
                    a = MFMA16(wih[c][0], h0B[0], bias[c]);
#pragma unroll
                    for (int kt = 1; kt < 4; kt++) a = MFMA16(wih[c][kt], h0B[kt], a);
                }
                accn[c] = a;
            }

            float h[4];
#pragma unroll
            for (int e = 0; e < 4; e++) {
                float ig = fsig(g4[0][e]);
                float fg = fsig(g4[1][e]);
                float gg = ftanh(g4[2][e]);
                float og = fsig(g4[3][e]);
                float cv = fg * cst[e] + ig * gg;
                cst[e] = cv;
                h[e] = og * ftanh(cv);
            }
            *(uint2*)(lds + (ph ^ 1) * 4096 + hwb) =
                make_uint2(bfp(h[0], h[1]), bfp(h[2], h[3]));
            if (ph == 1 && t == SEQ - 1)
                *(f32x4v*)(hfin + l15 * HID + j0) = f32x4v{h[0], h[1], h[2], h[3]};

            asm volatile("s_waitcnt lgkmcnt(0)\n\ts_barrier" ::: "memory");
#pragma unroll
            for (int c = 0; c < 4; c++) acc[c] = accn[c];
        }
    }
    __syncthreads();

    // fused FC: out[b][o] = relu(h1).fcw[o] + fcb[o]
    const int fb = tid >> 5, op = (tid & 31) * 2;
    float a0 = fcb[op], a1 = fcb[op + 1];
    const float4* w0 = (const float4*)(fcw + op * HID);
    const float4* w1 = (const float4*)(fcw + (op + 1) * HID);
    const float4* hv4 = (const float4*)(hfin + fb * HID);
#pragma unroll 8
    for (int k = 0; k < 32; k++) {
        float4 hv = hv4[k];
        float r0 = fmaxf(hv.x, 0.f), r1 = fmaxf(hv.y, 0.f);
        float r2 = fmaxf(hv.z, 0.f), r3 = fmaxf(hv.w, 0.f);
        float4 wa = w0[k], wb = w1[k];
        a0 += r0 * wa.x + r1 * wa.y + r2 * wa.z + r3 * wa.w;
        a1 += r0 * wb.x + r1 * wb.y + r2 * wb.z + r3 * wb.w;
    }
    out[(bb + fb) * 64 + op] = a0;
    out[(bb + fb) * 64 + op + 1] = a1;
}

// =============== single launch: blocks 0-31 = L0 producer, 32-63 = L1 consumer ===============
__global__ __launch_bounds__(512, 2) void lstm_pipe(
    const float* __restrict__ x,
    const float* __restrict__ Wih0, const float* __restrict__ Whh0,
    const float* __restrict__ bih0, const float* __restrict__ bhh0,
    const float* __restrict__ Wih1, const float* __restrict__ Whh1,
    const float* __restrict__ bih1, const float* __restrict__ bhh1,
    const float* __restrict__ fcw, const float* __restrict__ fcb,
    int* flags, unsigned short* hseq, float* __restrict__ out)
{
    __shared__ __align__(16) uint8_t lds[16384];
    if (blockIdx.x < 32) {
        l0_body(lds, x, Wih0, Whh0, bih0, bhh0, hseq, flags);
    } else {
        l1_body(lds, hseq, Wih1, Whh1, bih1, bhh1, fcw, fcb, out, flags);
    }
}

extern "C" void kernel_launch(void* const* d_in, const int* in_sizes, int n_in,
                              void* d_out, int out_size, void* d_ws, size_t ws_size,
                              hipStream_t stream) {
    const float* x    = (const float*)d_in[0];
    const float* Wih0 = (const float*)d_in[1];
    const float* Whh0 = (const float*)d_in[2];
    const float* bih0 = (const float*)d_in[3];
    const float* bhh0 = (const float*)d_in[4];
    const float* Wih1 = (const float*)d_in[5];
    const float* Whh1 = (const float*)d_in[6];
    const float* bih1 = (const float*)d_in[7];
    const float* bhh1 = (const float*)d_in[8];
    const float* fcw  = (const float*)d_in[9];
    const float* fcb  = (const float*)d_in[10];

    // ws: [0,4096) flags (zeroed per call), [4096, 4096+64MiB) hseq bf16 granules
    int* flags = (int*)d_ws;
    unsigned short* hseq = (unsigned short*)((char*)d_ws + 4096);
    hipMemsetAsync(d_ws, 0, 4096, stream);

    lstm_pipe<<<64, 512, 0, stream>>>(x, Wih0, Whh0, bih0, bhh0,
                                      Wih1, Whh1, bih1, bhh1, fcw, fcb,
                                      flags, hseq, (float*)d_out);
}